// Round 6
// baseline (665.139 us; speedup 1.0000x reference)
//
#include <hip/hip_runtime.h>

#define BATCH 16
#define CH    256
#define NPT   2048
#define DQK   32
#define OTOT  320   // 32 q + 32 k + 256 v
#define EPSB  1e-5f
#define SLOPE 0.2f

typedef __attribute__((ext_vector_type(8))) short bf16x8;
typedef __attribute__((ext_vector_type(4))) short bf16x4;
typedef __attribute__((ext_vector_type(4))) float f32x4;

__device__ __forceinline__ unsigned short f2bf(float f) {
    unsigned u = __float_as_uint(f);
    u = (u + 0x7FFFu + ((u >> 16) & 1u)) >> 16;
    return (unsigned short)u;
}
__device__ __forceinline__ float bf2f(unsigned short h) {
    return __uint_as_float(((unsigned)h) << 16);
}
__device__ __forceinline__ unsigned pack2(float a, float b) {
    return (unsigned)f2bf(a) | ((unsigned)f2bf(b) << 16);
}

// ---------------------------------------------------------------------------
// Kernel 0: split weights to Whi/Wlo bf16 [o][c] (A-frag layout) + bias Bv[o].
// grid 320 x 256.
__global__ __launch_bounds__(256) void prep_kernel(
    const float* __restrict__ qw, const float* __restrict__ qb,
    const float* __restrict__ kw, const float* __restrict__ kb,
    const float* __restrict__ vw, const float* __restrict__ vb,
    unsigned short* __restrict__ Whi, unsigned short* __restrict__ Wlo,
    float* __restrict__ Bv)
{
    int idx = blockIdx.x * 256 + threadIdx.x;   // < 81920
    int o = idx >> 8, c = idx & 255;
    float w;
    if (o < 32)      w = qw[(size_t)o * CH + c];
    else if (o < 64) w = kw[(size_t)(o - 32) * CH + c];
    else             w = vw[(size_t)(o - 64) * CH + c];
    unsigned short wh = f2bf(w);
    float rem = w - bf2f(wh);
    Whi[idx] = wh;
    Wlo[idx] = f2bf(rem);
    if (idx < OTOT) {
        int oo = idx;
        float bb;
        if (oo < 32)      bb = qb[oo];
        else if (oo < 64) bb = kb[oo - 32];
        else              bb = vb[oo - 64];
        Bv[oo] = bb;
    }
}

// ---------------------------------------------------------------------------
// Kernel 1: conv1x1 as bf16x3 MFMA GEMM (fp32-grade precision).
// Block: 64o x 128n for one b. grid (5, 16, 16), block 256 (waves 2o x 2n).
// Fused: bias, bf16 store, per-channel sum/sumsq atomics.
__global__ __launch_bounds__(256) void conv_kernel(
    const float* __restrict__ x,
    const unsigned short* __restrict__ Whi, const unsigned short* __restrict__ Wlo,
    const float* __restrict__ Bv,
    unsigned short* __restrict__ Ybf,
    float* __restrict__ Sum, float* __restrict__ Sq)
{
    int ob = blockIdx.x * 64;
    int n0 = blockIdx.y * 128;
    int b  = blockIdx.z;
    int tid = threadIdx.x;
    int w = tid >> 6, lane = tid & 63;
    int quad = lane >> 4, l16 = lane & 15;
    int wo = w >> 1, wn = w & 1;

    __shared__ unsigned short Xh[128][40];   // [n_local][c_local]
    __shared__ unsigned short Xl[128][40];

    int nl = tid & 127;       // n_local 0..127
    int ch = tid >> 7;        // c half: covers c_local = ch*16 .. +15
    const float* xb = x + (size_t)b * CH * NPT + n0 + nl;

    f32x4 acc[2][4];
#pragma unroll
    for (int ot = 0; ot < 2; ++ot)
#pragma unroll
        for (int nt = 0; nt < 4; ++nt)
            acc[ot][nt] = (f32x4){0.f, 0.f, 0.f, 0.f};

    float xv[16];
#pragma unroll
    for (int i = 0; i < 16; ++i)
        xv[i] = xb[(size_t)(ch * 16 + i) * NPT];

    for (int ks = 0; ks < 8; ++ks) {
        __syncthreads();
#pragma unroll
        for (int g = 0; g < 4; ++g) {
            ushort4 h4, l4;
            unsigned short* ph = (unsigned short*)&h4;
            unsigned short* pl = (unsigned short*)&l4;
#pragma unroll
            for (int j = 0; j < 4; ++j) {
                float f = xv[g * 4 + j];
                unsigned short h = f2bf(f);
                ph[j] = h;
                pl[j] = f2bf(f - bf2f(h));
            }
            *(ushort4*)&Xh[nl][ch * 16 + g * 4] = h4;
            *(ushort4*)&Xl[nl][ch * 16 + g * 4] = l4;
        }
        __syncthreads();

        if (ks < 7) {
#pragma unroll
            for (int i = 0; i < 16; ++i)
                xv[i] = xb[(size_t)((ks + 1) * 32 + ch * 16 + i) * NPT];
        }

        bf16x8 ah[2], al[2];
#pragma unroll
        for (int ot = 0; ot < 2; ++ot) {
            size_t orow = (size_t)(ob + wo * 32 + ot * 16 + l16) * 256 + ks * 32 + quad * 8;
            ah[ot] = *(const bf16x8*)(Whi + orow);
            al[ot] = *(const bf16x8*)(Wlo + orow);
        }
#pragma unroll
        for (int nt = 0; nt < 4; ++nt) {
            int nr = wn * 64 + nt * 16 + l16;
            bf16x8 bh = *(const bf16x8*)&Xh[nr][quad * 8];
            bf16x8 bl = *(const bf16x8*)&Xl[nr][quad * 8];
#pragma unroll
            for (int ot = 0; ot < 2; ++ot) {
                acc[ot][nt] = __builtin_amdgcn_mfma_f32_16x16x32_bf16(ah[ot], bh, acc[ot][nt], 0, 0, 0);
                acc[ot][nt] = __builtin_amdgcn_mfma_f32_16x16x32_bf16(ah[ot], bl, acc[ot][nt], 0, 0, 0);
                acc[ot][nt] = __builtin_amdgcn_mfma_f32_16x16x32_bf16(al[ot], bh, acc[ot][nt], 0, 0, 0);
            }
        }
    }

#pragma unroll
    for (int ot = 0; ot < 2; ++ot) {
        int obase = ob + wo * 32 + ot * 16 + quad * 4;
        float bias[4], sv[4], sq[4];
#pragma unroll
        for (int r = 0; r < 4; ++r) {
            bias[r] = Bv[obase + r];
            sv[r] = 0.f; sq[r] = 0.f;
        }
#pragma unroll
        for (int nt = 0; nt < 4; ++nt) {
            int n = n0 + wn * 64 + nt * 16 + l16;
#pragma unroll
            for (int r = 0; r < 4; ++r) {
                float v = acc[ot][nt][r] + bias[r];
                Ybf[((size_t)b * OTOT + obase + r) * NPT + n] = f2bf(v);
                sv[r] += v; sq[r] += v * v;
            }
        }
#pragma unroll
        for (int r = 0; r < 4; ++r) {
            float a = sv[r], q = sq[r];
            a += __shfl_xor(a, 1); q += __shfl_xor(q, 1);
            a += __shfl_xor(a, 2); q += __shfl_xor(q, 2);
            a += __shfl_xor(a, 4); q += __shfl_xor(q, 4);
            a += __shfl_xor(a, 8); q += __shfl_xor(q, 8);
            if (l16 == 0) {
                atomicAdd(&Sum[obase + r], a);
                atomicAdd(&Sq[obase + r], q);
            }
        }
    }
}

// ---------------------------------------------------------------------------
// Kernel 2: finalize BN affine: A[o], Cc[o].  1 block, 320 threads.
__global__ __launch_bounds__(320) void finalize_kernel(
    const float* __restrict__ Sum, const float* __restrict__ Sq,
    const float* __restrict__ qg, const float* __restrict__ qbe,
    const float* __restrict__ kg, const float* __restrict__ kbe,
    const float* __restrict__ vg, const float* __restrict__ vbe,
    float* __restrict__ A, float* __restrict__ Cc)
{
    int o = threadIdx.x;
    if (o >= OTOT) return;
    const float inv = 1.0f / (BATCH * NPT);
    float mean = Sum[o] * inv;
    float var  = Sq[o] * inv - mean * mean;
    float g, be;
    if (o < 32)      { g = qg[o];      be = qbe[o];      }
    else if (o < 64) { g = kg[o - 32]; be = kbe[o - 32]; }
    else             { g = vg[o - 64]; be = vbe[o - 64]; }
    float a = g * rsqrtf(var + EPSB);
    A[o]  = a;
    Cc[o] = be - mean * a;
}

// ---------------------------------------------------------------------------
// Kernel 3: pack pass — v: affine+LeakyReLU -> Vbf [b][c][n];
//                       q/k: affine + transpose -> QKt [b][n][64].
// grid (32, 16), block 256.
__global__ __launch_bounds__(256) void pack_kernel(
    const unsigned short* __restrict__ Ybf,
    const float* __restrict__ A, const float* __restrict__ Cc,
    unsigned short* __restrict__ QKt, unsigned short* __restrict__ Vbf)
{
    int b = blockIdx.y, n0 = blockIdx.x * 64;
    int tid = threadIdx.x;

    for (int e = tid; e < 4096; e += 256) {
        int c = e >> 4, n4 = (e & 15) * 4;
        ushort4 v4 = *(const ushort4*)(Ybf + ((size_t)b * OTOT + 64 + c) * NPT + n0 + n4);
        float a = A[64 + c], cc = Cc[64 + c];
        ushort4 w4;
        unsigned short* pi = (unsigned short*)&v4;
        unsigned short* po = (unsigned short*)&w4;
#pragma unroll
        for (int i = 0; i < 4; ++i) {
            float y = bf2f(pi[i]) * a + cc;
            y = (y > 0.f) ? y : SLOPE * y;
            po[i] = f2bf(y);
        }
        *(ushort4*)(Vbf + ((size_t)b * CH + c) * NPT + n0 + n4) = w4;
    }

    __shared__ unsigned short T[64][72];
    for (int e = tid; e < 1024; e += 256) {
        int o = e >> 4, n4 = (e & 15) * 4;
        ushort4 v4 = *(const ushort4*)(Ybf + ((size_t)b * OTOT + o) * NPT + n0 + n4);
        float a = A[o], cc = Cc[o];
        unsigned short* pi = (unsigned short*)&v4;
#pragma unroll
        for (int i = 0; i < 4; ++i)
            T[n4 + i][o] = f2bf(bf2f(pi[i]) * a + cc);
    }
    __syncthreads();
    for (int e = tid; e < 1024; e += 256) {
        int nn = e >> 4, o4 = (e & 15) * 4;
        ushort4 v4 = *(const ushort4*)&T[nn][o4];
        *(ushort4*)(QKt + ((size_t)b * NPT + n0 + nn) * 64 + o4) = v4;
    }
}

// ---------------------------------------------------------------------------
// Kernel 4: MFMA flash attention — fully register-resident P.
// Trick: C-frag of S^T (key=quad*4+r, query=l16) IS the B-frag of
// mfma_f32_16x16x16bf16_1k (k=quad*4+i, col=l16) -> no LDS/shfl/barrier.
// Block: 64 queries x 256 channels x all keys; wave w owns queries w*16..+15.
// All 4 waves stream the SAME 16-key K/V tiles (L1 reuse), double-buffered.
// grid 512 (b paired per XCD so per-b V+K ~1.3MB stays L2-resident), block 256.
__global__ __launch_bounds__(256, 2) void attn_kernel(
    const unsigned short* __restrict__ QKt,
    const unsigned short* __restrict__ Vbf,
    const float* __restrict__ x,
    float* __restrict__ out)
{
    int L = blockIdx.x;
    int xcd = L & 7, idx = L >> 3;        // idx 0..63
    int b = xcd * 2 + (idx & 1);          // 2 batches per XCD; co-resident blocks share b
    int n0 = (idx >> 1) * 64;             // 32 query tiles per b

    int tid = threadIdx.x;
    int w = tid >> 6, lane = tid & 63;
    int quad = lane >> 4, l16 = lane & 15;

    const unsigned short* QK = QKt + (size_t)b * NPT * 64;
    const unsigned short* V  = Vbf + (size_t)b * CH * NPT;

    int q = n0 + w * 16 + l16;
    // Q B-frag (resident): B[d=quad*8+j][col=q=l16]
    bf16x8 qf = *(const bf16x8*)(QK + (size_t)q * 64 + quad * 8);

    f32x4 o[16];
#pragma unroll
    for (int ct = 0; ct < 16; ++ct) o[ct] = (f32x4){0.f, 0.f, 0.f, 0.f};
    float rsum = 0.f;
    const f32x4 zero4 = (f32x4){0.f, 0.f, 0.f, 0.f};

    // K A-frag loader: A[m=l16][d=quad*8+j] (k-part at col 32)
    auto loadK = [&](int m0) -> bf16x8 {
        return *(const bf16x8*)(QK + (size_t)(m0 + l16) * 64 + 32 + quad * 8);
    };
    // V A-frags (K=16): A[c=ct*16+l16][m=m0+quad*4+i] — ushort4 (8B) each
    auto loadV = [&](ushort4* dst, int m0) {
#pragma unroll
        for (int ct = 0; ct < 16; ++ct)
            dst[ct] = *(const ushort4*)(V + (size_t)(ct * 16 + l16) * NPT + m0 + quad * 4);
    };
    // one 16-key step: S^T -> exp -> P directly as PV B-operand
    auto step = [&](const bf16x8& kf, const ushort4* vq) {
        f32x4 st = __builtin_amdgcn_mfma_f32_16x16x32_bf16(kf, qf, zero4, 0, 0, 0);
        float p0 = __expf(st[0]), p1 = __expf(st[1]);
        float p2 = __expf(st[2]), p3 = __expf(st[3]);   // max-free: |s| <~ 40 << 88
        rsum += (p0 + p1) + (p2 + p3);
        union { unsigned u[2]; bf16x4 v; } pb;
        pb.u[0] = pack2(p0, p1);
        pb.u[1] = pack2(p2, p3);
#pragma unroll
        for (int ct = 0; ct < 16; ++ct) {
            union { ushort4 s; bf16x4 v; } vf;
            vf.s = vq[ct];
            o[ct] = __builtin_amdgcn_mfma_f32_16x16x16bf16_1k(vf.v, pb.v, o[ct], 0, 0, 0);
        }
    };

    bf16x8 kf0 = loadK(0), kf1;
    ushort4 vq0[16], vq1[16];
    loadV(vq0, 0);

    for (int t2 = 0; t2 < 64; ++t2) {
        int m1 = (t2 * 2 + 1) * 16;
        int m2 = ((t2 * 2 + 2) & 127) * 16;   // wraps harmlessly on last iter
        kf1 = loadK(m1);
        loadV(vq1, m1);
        step(kf0, vq0);
        kf0 = loadK(m2);
        loadV(vq0, m2);
        step(kf1, vq1);
    }

    // per-query denominator: sum the 4 quad-partials (one-time cross-lane)
    rsum += __shfl_xor(rsum, 16);
    rsum += __shfl_xor(rsum, 32);
    float rtot = 1.0f / rsum;

    // epilogue: lane holds O[c=ct*16+quad*4+r][query q]; + residual
#pragma unroll
    for (int ct = 0; ct < 16; ++ct) {
        int cbase = ct * 16 + quad * 4;
#pragma unroll
        for (int r = 0; r < 4; ++r) {
            size_t gidx = ((size_t)b * CH + cbase + r) * NPT + q;
            out[gidx] = o[ct][r] * rtot + x[gidx];
        }
    }
}

// ---------------------------------------------------------------------------
extern "C" void kernel_launch(void* const* d_in, const int* in_sizes, int n_in,
                              void* d_out, int out_size, void* d_ws, size_t ws_size,
                              hipStream_t stream)
{
    const float* x   = (const float*)d_in[0];
    const float* qw  = (const float*)d_in[1];
    const float* qb  = (const float*)d_in[2];
    const float* qg  = (const float*)d_in[3];
    const float* qbe = (const float*)d_in[4];
    const float* kw  = (const float*)d_in[5];
    const float* kb  = (const float*)d_in[6];
    const float* kg  = (const float*)d_in[7];
    const float* kbe = (const float*)d_in[8];
    const float* vw  = (const float*)d_in[9];
    const float* vb  = (const float*)d_in[10];
    const float* vg  = (const float*)d_in[11];
    const float* vbe = (const float*)d_in[12];
    float* out = (float*)d_out;

    unsigned short* Ybf = (unsigned short*)d_ws;
    unsigned short* QKt = Ybf + (size_t)BATCH * OTOT * NPT;          // 10,485,760 elems
    unsigned short* Vbf = QKt + (size_t)BATCH * NPT * 64;            // +2,097,152
    float* tail = (float*)(Vbf + (size_t)BATCH * CH * NPT);          // +8,388,608
    float* Sum = tail;
    float* Sq  = tail + OTOT;
    float* A   = tail + 2 * OTOT;
    float* Cc  = tail + 3 * OTOT;
    unsigned short* Whi = QKt;                         // overlay, consumed pre-pack
    unsigned short* Wlo = Whi + (size_t)CH * OTOT;
    float* Bv = (float*)(Wlo + (size_t)CH * OTOT);

    hipMemsetAsync(Sum, 0, 2 * OTOT * sizeof(float), stream);
    prep_kernel    <<<320, 256, 0, stream>>>(qw, qb, kw, kb, vw, vb, Whi, Wlo, Bv);
    conv_kernel    <<<dim3(5, 16, 16), 256, 0, stream>>>(x, Whi, Wlo, Bv, Ybf, Sum, Sq);
    finalize_kernel<<<1, 320, 0, stream>>>(Sum, Sq, qg, qbe, kg, kbe, vg, vbe, A, Cc);
    pack_kernel    <<<dim3(NPT / 64, BATCH), 256, 0, stream>>>(Ybf, A, Cc, QKt, Vbf);
    attn_kernel    <<<512, 256, 0, stream>>>(QKt, Vbf, x, out);
}